// Round 7
// baseline (13660.439 us; speedup 1.0000x reference)
//
#include <hip/hip_runtime.h>
#include <stdint.h>

#define LAYERS    5
#define INPUT_DIM 512
#define CODE_DIM  2048
#define BATCH     32768
#define KSP       32

#define BM  128
#define BN  128
#define BKT 32

#define GLOAD_LDS16(dst, src) \
    __builtin_amdgcn_global_load_lds((const __attribute__((address_space(1))) uint32_t*)(src), \
                                     (__attribute__((address_space(3))) uint32_t*)(dst), 16, 0, 0)

// ---------------------------------------------------------------------------
// D [512][2048] -> Dt [2048][512]  (bit copy)
__global__ __launch_bounds__(256) void transpose_512x2048_kernel(const float* __restrict__ src,
                                                                 float* __restrict__ dst)
{
    __shared__ float tile[32][33];
    const int tx = threadIdx.x;
    const int ty = threadIdx.y;
    const int cb = blockIdx.x * 32;
    const int ib = blockIdx.y * 32;
    #pragma unroll
    for (int j = 0; j < 32; j += 8)
        tile[ty + j][tx] = src[(size_t)(ib + ty + j) * CODE_DIM + cb + tx];
    __syncthreads();
    #pragma unroll
    for (int j = 0; j < 32; j += 8)
        dst[(size_t)(cb + ty + j) * INPUT_DIM + ib + tx] = tile[tx][ty + j];
}

// ---------------------------------------------------------------------------
// u = x@Wl (+ z@Sl for l>0).  Arithmetic contract (np/BLAS-faithful):
//  - x@W: one f32 accumulator per element, k = 0..511 strictly ascending fmaf
//  - z@S: separate zero-init accumulator, 32 nz folded ascending-index, fmaf
//  - u = xw + zs (single add)
// Tile 128x128, 256 threads, per-thread 8 rows x 8 cols as two quads at
// cn and cn+64 (cn=(t&15)*4) -> every LDS B-read is 2-way/bank = free.
// 8x8 tile: 92 VGPR in r4, no spill — do NOT enlarge (r5/r6: compiler caps
// at 128/112 VGPR and demotes acc to scratch, +7 GB HBM traffic).
__global__ __launch_bounds__(256) void gemm_layer_kernel(
    const float* __restrict__ x, const float* __restrict__ Wl,
    const float* __restrict__ Sl, const int* __restrict__ zidx,
    const float* __restrict__ zval, float* __restrict__ u)
{
    __shared__ float As[BKT][BM + 4];   // transposed: As[k][m]; reads broadcast
    __shared__ float Bs[BKT][BN];       // linear (global_load_lds dest, rows 512B)

    const int t    = threadIdx.x;
    const int lane = t & 63;
    const int wid  = t >> 6;
    const int c0   = blockIdx.x * BN;
    const int r0   = blockIdx.y * BM;
    const int tm0  = (t >> 4) * 8;        // 8 rows
    const int cn   = (t & 15) * 4;        // col quads at cn, cn+64

    float acc[8][8];
    #pragma unroll
    for (int i = 0; i < 8; ++i)
        #pragma unroll
        for (int j = 0; j < 8; ++j) acc[i][j] = 0.f;

    for (int kt = 0; kt < INPUT_DIM; kt += BKT) {
        __syncthreads();   // previous tile consumed before overwrite
        // --- stage A: 128 rows x 32 k, transposed into As[k][m] ---
        #pragma unroll
        for (int i = 0; i < 4; ++i) {
            int f   = t * 4 + i;          // 0..1023 float4s
            int row = f >> 3, kq = f & 7;
            float4 v = *(const float4*)&x[(size_t)(r0 + row) * INPUT_DIM + kt + kq * 4];
            As[kq * 4 + 0][row] = v.x;
            As[kq * 4 + 1][row] = v.y;
            As[kq * 4 + 2][row] = v.z;
            As[kq * 4 + 3][row] = v.w;
        }
        // --- stage B: 32 rows x 128 cols via async global->LDS (2 rows/instr) ---
        #pragma unroll
        for (int s = 0; s < 4; ++s) {
            int r = wid * 8 + s * 2;      // this wave's rows r, r+1
            GLOAD_LDS16(&Bs[r][0],
                        Wl + (size_t)(kt + r + (lane >> 5)) * CODE_DIM + c0 + (lane & 31) * 4);
        }
        __syncthreads();   // compiler drains vmcnt/lgkmcnt before barrier

        for (int kk = 0; kk < BKT; ++kk) {   // strictly ascending k chain
            float a[8];
            *(float4*)&a[0] = *(const float4*)&As[kk][tm0];
            *(float4*)&a[4] = *(const float4*)&As[kk][tm0 + 4];
            #pragma unroll
            for (int q = 0; q < 2; ++q) {    // quads: conflict-free B reads
                float4 b = *(const float4*)&Bs[kk][cn + q * 64];
                #pragma unroll
                for (int i = 0; i < 8; ++i) {
                    acc[i][q * 4 + 0] = fmaf(a[i], b.x, acc[i][q * 4 + 0]);
                    acc[i][q * 4 + 1] = fmaf(a[i], b.y, acc[i][q * 4 + 1]);
                    acc[i][q * 4 + 2] = fmaf(a[i], b.z, acc[i][q * 4 + 2]);
                    acc[i][q * 4 + 3] = fmaf(a[i], b.w, acc[i][q * 4 + 3]);
                }
            }
        }
    }

    if (Sl != nullptr) {
        #pragma unroll 1
        for (int i = 0; i < 8; ++i) {
            const int r = r0 + tm0 + i;
            const int*   ip = zidx + (size_t)r * KSP;   // ascending code index
            const float* vp = zval + (size_t)r * KSP;
            float zacc[8];
            #pragma unroll
            for (int j = 0; j < 8; ++j) zacc[j] = 0.f;
            for (int k = 0; k < KSP; ++k) {             // global k order ascending
                int   j = ip[k];
                float v = vp[k];
                const float* srow = Sl + (size_t)j * CODE_DIM + c0 + cn;
                float4 s0 = *(const float4*)&srow[0];
                float4 s1 = *(const float4*)&srow[64];
                zacc[0] = fmaf(v, s0.x, zacc[0]);
                zacc[1] = fmaf(v, s0.y, zacc[1]);
                zacc[2] = fmaf(v, s0.z, zacc[2]);
                zacc[3] = fmaf(v, s0.w, zacc[3]);
                zacc[4] = fmaf(v, s1.x, zacc[4]);
                zacc[5] = fmaf(v, s1.y, zacc[5]);
                zacc[6] = fmaf(v, s1.z, zacc[6]);
                zacc[7] = fmaf(v, s1.w, zacc[7]);
            }
            #pragma unroll
            for (int j = 0; j < 8; ++j)     // single add: u = xw + zs
                acc[i][j] = acc[i][j] + zacc[j];
        }
    }

    #pragma unroll
    for (int i = 0; i < 8; ++i) {
        float* up = u + (size_t)(r0 + tm0 + i) * CODE_DIM + c0 + cn;
        *(float4*)&up[0]  = make_float4(acc[i][0], acc[i][1], acc[i][2], acc[i][3]);
        *(float4*)&up[64] = make_float4(acc[i][4], acc[i][5], acc[i][6], acc[i][7]);
    }
}

// ---------------------------------------------------------------------------
// top-32 by |u| (desc, tie -> lower index), one WAVE per row, registers only.
// Output written index-sorted.
__global__ __launch_bounds__(256) void topk32_wave_kernel(const float* __restrict__ u,
                                                          int* __restrict__ zidx,
                                                          float* __restrict__ zval)
{
    const int lane = threadIdx.x & 63;
    const int row  = blockIdx.x * 4 + (threadIdx.x >> 6);
    const float* ur = u + (size_t)row * CODE_DIM;

    uint32_t a[32];
    #pragma unroll
    for (int q = 0; q < 8; ++q) {
        float4 v = *(const float4*)&ur[lane * 32 + q * 4];
        a[q * 4 + 0] = __float_as_uint(v.x) & 0x7fffffffu;
        a[q * 4 + 1] = __float_as_uint(v.y) & 0x7fffffffu;
        a[q * 4 + 2] = __float_as_uint(v.z) & 0x7fffffffu;
        a[q * 4 + 3] = __float_as_uint(v.w) & 0x7fffffffu;
    }

    uint32_t bf = 0; int bj = 32;
    #pragma unroll
    for (int j = 0; j < 32; ++j)
        if (bj == 32 || a[j] > bf) { bf = a[j]; bj = j; }

    uint32_t wi = 0xFFFFFFFFu;
    for (int it = 0; it < KSP; ++it) {
        uint32_t cf = bf;
        uint32_t ci = (bj < 32) ? (uint32_t)(lane * 32 + bj) : 0x7FFFFFFFu;
        #pragma unroll
        for (int off = 1; off <= 32; off <<= 1) {
            uint32_t of = __shfl_xor(cf, off);
            uint32_t oi = __shfl_xor(ci, off);
            if (of > cf || (of == cf && oi < ci)) { cf = of; ci = oi; }
        }
        if (lane == it) wi = ci;
        if ((ci >> 5) == (uint32_t)lane) {    // winner rescans strictly below (cf,ci)
            uint32_t nbf = 0; int nbj = 32;
            #pragma unroll
            for (int j = 0; j < 32; ++j) {
                uint32_t gi = (uint32_t)(lane * 32 + j);
                bool less = (a[j] < cf) || (a[j] == cf && gi > ci);
                if (less && (nbj == 32 || a[j] > nbf)) { nbf = a[j]; nbj = j; }
            }
            bf = nbf; bj = nbj;
        }
    }

    int rank = 0;
    #pragma unroll
    for (int m = 0; m < 32; ++m) {
        uint32_t om = __shfl(wi, m);
        rank += (om < wi) ? 1 : 0;
    }
    if (lane < KSP) {
        int idx = (int)wi;
        zidx[(size_t)row * KSP + rank] = idx;
        zval[(size_t)row * KSP + rank] = ur[idx];
    }
}

// ---------------------------------------------------------------------------
__global__ __launch_bounds__(256) void zfill_scatter_kernel(const int* __restrict__ zidx,
                                                            const float* __restrict__ zval,
                                                            float* __restrict__ zden)
{
    const int t  = threadIdx.x;
    const int r0 = blockIdx.x * 8;
    float* base = zden + (size_t)r0 * CODE_DIM;
    const float4 zero = make_float4(0.f, 0.f, 0.f, 0.f);
    for (int q = t; q < 8 * CODE_DIM / 4; q += 256)
        *(float4*)&base[q * 4] = zero;
    __syncthreads();
    const int rl = t >> 5, k = t & 31;
    int   idx = zidx[(size_t)(r0 + rl) * KSP + k];
    float v   = zval[(size_t)(r0 + rl) * KSP + k];
    base[(size_t)rl * CODE_DIM + idx] = v;
}

// ---------------------------------------------------------------------------
// recon: ascending-index fold of 32 nonzeros, f32 fmaf (np z@D.T faithful)
__global__ __launch_bounds__(128) void recon_kernel(const int* __restrict__ zidx,
                                                    const float* __restrict__ zval,
                                                    const float* __restrict__ Dt,
                                                    float* __restrict__ recon)
{
    const int t   = threadIdx.x;
    const int row = blockIdx.x;
    float4 acc = make_float4(0.f, 0.f, 0.f, 0.f);
    const int*   ip = zidx + (size_t)row * KSP;
    const float* vp = zval + (size_t)row * KSP;
    for (int k = 0; k < KSP; ++k) {
        int   j = ip[k];
        float v = vp[k];
        float4 d = *(const float4*)&Dt[(size_t)j * INPUT_DIM + t * 4];
        acc.x = fmaf(v, d.x, acc.x);
        acc.y = fmaf(v, d.y, acc.y);
        acc.z = fmaf(v, d.z, acc.z);
        acc.w = fmaf(v, d.w, acc.w);
    }
    *(float4*)&recon[(size_t)row * INPUT_DIM + t * 4] = acc;
}

// ---------------------------------------------------------------------------
extern "C" void kernel_launch(void* const* d_in, const int* in_sizes, int n_in,
                              void* d_out, int out_size, void* d_ws, size_t ws_size,
                              hipStream_t stream)
{
    const float* x = (const float*)d_in[0];
    const float* W = (const float*)d_in[1];   // [5][512][2048]
    const float* S = (const float*)d_in[2];   // [5][2048][2048]
    const float* D = (const float*)d_in[3];   // [512][2048]

    float* recon = (float*)d_out;
    float* zden  = (float*)d_out + (size_t)BATCH * INPUT_DIM;  // u scratch, then dense z

    int*   zidx = (int*)d_ws;
    float* zval = (float*)((char*)d_ws + (size_t)BATCH * KSP * 4);
    float* Dt   = (float*)((char*)d_ws + (size_t)2 * BATCH * KSP * 4);

    transpose_512x2048_kernel<<<dim3(CODE_DIM / 32, INPUT_DIM / 32), dim3(32, 8), 0, stream>>>(D, Dt);

    for (int l = 0; l < LAYERS; ++l) {
        const float* Wl = W + (size_t)l * INPUT_DIM * CODE_DIM;
        const float* Sl = (l == 0) ? nullptr : S + (size_t)l * CODE_DIM * CODE_DIM;
        gemm_layer_kernel<<<dim3(CODE_DIM / BN, BATCH / BM), 256, 0, stream>>>(
            x, Wl, Sl, (l == 0) ? nullptr : zidx, (l == 0) ? nullptr : zval, zden);
        topk32_wave_kernel<<<BATCH / 4, 256, 0, stream>>>(zden, zidx, zval);
    }

    zfill_scatter_kernel<<<BATCH / 8, 256, 0, stream>>>(zidx, zval, zden);
    recon_kernel<<<BATCH, 128, 0, stream>>>(zidx, zval, Dt, recon);
}

// Round 8
// 8744.089 us; speedup vs baseline: 1.5622x; 1.5622x over previous
//
#include <hip/hip_runtime.h>
#include <stdint.h>

#define LAYERS    5
#define INPUT_DIM 512
#define CODE_DIM  2048
#define BATCH     32768
#define KSP       32

#define BM  128
#define BN  128
#define BKT 16

// ---------------------------------------------------------------------------
// D [512][2048] -> Dt [2048][512]  (bit copy)
__global__ __launch_bounds__(256) void transpose_512x2048_kernel(const float* __restrict__ src,
                                                                 float* __restrict__ dst)
{
    __shared__ float tile[32][33];
    const int tx = threadIdx.x;
    const int ty = threadIdx.y;
    const int cb = blockIdx.x * 32;
    const int ib = blockIdx.y * 32;
    #pragma unroll
    for (int j = 0; j < 32; j += 8)
        tile[ty + j][tx] = src[(size_t)(ib + ty + j) * CODE_DIM + cb + tx];
    __syncthreads();
    #pragma unroll
    for (int j = 0; j < 32; j += 8)
        dst[(size_t)(cb + ty + j) * INPUT_DIM + ib + tx] = tile[tx][ty + j];
}

// ---------------------------------------------------------------------------
// u = x@Wl (+ z@Sl for l>0).  Arithmetic contract (np/BLAS-faithful):
//  - x@W: one f32 accumulator per element, k = 0..511 strictly ascending fmaf
//  - z@S: separate zero-init accumulator, 32 nz folded ascending-index, fmaf
//  - u = xw + zs (single add)
// EXACT r4 structure (92 VGPR, no spill) with ONE change: thread cols are
// cn=(t&15)*4 and cn+64 (was (t&15)*8..+7) -> every Bs ds_read_b128 by a
// 16-lane group covers 64 consecutive dwords = 2 lanes/bank = conflict-free.
// WARNING (r5/r6/r7 lessons): acc[][] must ONLY be indexed from fully
// unrolled loops (runtime index -> scratch, 8 GB spill traffic); do not
// enlarge past 8x8 (compiler caps VGPR at ~128 and spills).
__global__ __launch_bounds__(256) void gemm_layer_kernel(
    const float* __restrict__ x, const float* __restrict__ Wl,
    const float* __restrict__ Sl, const int* __restrict__ zidx,
    const float* __restrict__ zval, float* __restrict__ u)
{
    __shared__ float As[BKT][BM + 4];   // transposed: As[k][m]; reads broadcast
    __shared__ float Bs[BKT][BN + 4];

    const int t   = threadIdx.x;
    const int c0  = blockIdx.x * BN;
    const int r0  = blockIdx.y * BM;
    const int tm0 = (t >> 4) * 8;         // 8 rows
    const int cn  = (t & 15) * 4;         // col quads at cn, cn+64

    float acc[8][8];
    #pragma unroll
    for (int i = 0; i < 8; ++i)
        #pragma unroll
        for (int j = 0; j < 8; ++j) acc[i][j] = 0.f;

    for (int kt = 0; kt < INPUT_DIM; kt += BKT) {
        #pragma unroll
        for (int i = 0; i < 2; ++i) {
            int f   = t * 2 + i;
            int row = f >> 2, kq = f & 3;
            float4 v = *(const float4*)&x[(size_t)(r0 + row) * INPUT_DIM + kt + kq * 4];
            As[kq * 4 + 0][row] = v.x;
            As[kq * 4 + 1][row] = v.y;
            As[kq * 4 + 2][row] = v.z;
            As[kq * 4 + 3][row] = v.w;
        }
        #pragma unroll
        for (int i = 0; i < 2; ++i) {
            int g  = t * 2 + i;
            int kr = g >> 5, cq = g & 31;
            *(float4*)&Bs[kr][cq * 4] =
                *(const float4*)&Wl[(size_t)(kt + kr) * CODE_DIM + c0 + cq * 4];
        }
        __syncthreads();
        #pragma unroll
        for (int kk = 0; kk < BKT; ++kk) {      // strictly ascending k chain
            float a[8], b[8];
            *(float4*)&a[0] = *(const float4*)&As[kk][tm0];
            *(float4*)&a[4] = *(const float4*)&As[kk][tm0 + 4];
            *(float4*)&b[0] = *(const float4*)&Bs[kk][cn];        // conflict-free
            *(float4*)&b[4] = *(const float4*)&Bs[kk][cn + 64];   // conflict-free
            #pragma unroll
            for (int i = 0; i < 8; ++i)
                #pragma unroll
                for (int j = 0; j < 8; ++j)
                    acc[i][j] = fmaf(a[i], b[j], acc[i][j]);
        }
        __syncthreads();
    }

    if (Sl != nullptr) {
        #pragma unroll
        for (int i = 0; i < 8; ++i) {
            const int r = r0 + tm0 + i;
            const int*   ip = zidx + (size_t)r * KSP;   // ascending code index
            const float* vp = zval + (size_t)r * KSP;
            float zacc[8];
            #pragma unroll
            for (int j = 0; j < 8; ++j) zacc[j] = 0.f;
            for (int k = 0; k < KSP; ++k) {             // global k order ascending
                int   j = ip[k];
                float v = vp[k];
                const float* srow = Sl + (size_t)j * CODE_DIM + c0 + cn;
                float4 s0 = *(const float4*)&srow[0];
                float4 s1 = *(const float4*)&srow[64];
                zacc[0] = fmaf(v, s0.x, zacc[0]);
                zacc[1] = fmaf(v, s0.y, zacc[1]);
                zacc[2] = fmaf(v, s0.z, zacc[2]);
                zacc[3] = fmaf(v, s0.w, zacc[3]);
                zacc[4] = fmaf(v, s1.x, zacc[4]);
                zacc[5] = fmaf(v, s1.y, zacc[5]);
                zacc[6] = fmaf(v, s1.z, zacc[6]);
                zacc[7] = fmaf(v, s1.w, zacc[7]);
            }
            #pragma unroll
            for (int j = 0; j < 8; ++j)     // single add: u = xw + zs
                acc[i][j] = acc[i][j] + zacc[j];
        }
    }

    #pragma unroll
    for (int i = 0; i < 8; ++i) {
        float* up = u + (size_t)(r0 + tm0 + i) * CODE_DIM + c0 + cn;
        *(float4*)&up[0]  = make_float4(acc[i][0], acc[i][1], acc[i][2], acc[i][3]);
        *(float4*)&up[64] = make_float4(acc[i][4], acc[i][5], acc[i][6], acc[i][7]);
    }
}

// ---------------------------------------------------------------------------
// top-32 by |u| (desc, tie -> lower index), one WAVE per row, registers only.
// Output written index-sorted.
__global__ __launch_bounds__(256) void topk32_wave_kernel(const float* __restrict__ u,
                                                          int* __restrict__ zidx,
                                                          float* __restrict__ zval)
{
    const int lane = threadIdx.x & 63;
    const int row  = blockIdx.x * 4 + (threadIdx.x >> 6);
    const float* ur = u + (size_t)row * CODE_DIM;

    uint32_t a[32];
    #pragma unroll
    for (int q = 0; q < 8; ++q) {
        float4 v = *(const float4*)&ur[lane * 32 + q * 4];
        a[q * 4 + 0] = __float_as_uint(v.x) & 0x7fffffffu;
        a[q * 4 + 1] = __float_as_uint(v.y) & 0x7fffffffu;
        a[q * 4 + 2] = __float_as_uint(v.z) & 0x7fffffffu;
        a[q * 4 + 3] = __float_as_uint(v.w) & 0x7fffffffu;
    }

    uint32_t bf = 0; int bj = 32;
    #pragma unroll
    for (int j = 0; j < 32; ++j)
        if (bj == 32 || a[j] > bf) { bf = a[j]; bj = j; }

    uint32_t wi = 0xFFFFFFFFu;
    for (int it = 0; it < KSP; ++it) {
        uint32_t cf = bf;
        uint32_t ci = (bj < 32) ? (uint32_t)(lane * 32 + bj) : 0x7FFFFFFFu;
        #pragma unroll
        for (int off = 1; off <= 32; off <<= 1) {
            uint32_t of = __shfl_xor(cf, off);
            uint32_t oi = __shfl_xor(ci, off);
            if (of > cf || (of == cf && oi < ci)) { cf = of; ci = oi; }
        }
        if (lane == it) wi = ci;
        if ((ci >> 5) == (uint32_t)lane) {    // winner rescans strictly below (cf,ci)
            uint32_t nbf = 0; int nbj = 32;
            #pragma unroll
            for (int j = 0; j < 32; ++j) {
                uint32_t gi = (uint32_t)(lane * 32 + j);
                bool less = (a[j] < cf) || (a[j] == cf && gi > ci);
                if (less && (nbj == 32 || a[j] > nbf)) { nbf = a[j]; nbj = j; }
            }
            bf = nbf; bj = nbj;
        }
    }

    int rank = 0;
    #pragma unroll
    for (int m = 0; m < 32; ++m) {
        uint32_t om = __shfl(wi, m);
        rank += (om < wi) ? 1 : 0;
    }
    if (lane < KSP) {
        int idx = (int)wi;
        zidx[(size_t)row * KSP + rank] = idx;
        zval[(size_t)row * KSP + rank] = ur[idx];
    }
}

// ---------------------------------------------------------------------------
__global__ __launch_bounds__(256) void zfill_scatter_kernel(const int* __restrict__ zidx,
                                                            const float* __restrict__ zval,
                                                            float* __restrict__ zden)
{
    const int t  = threadIdx.x;
    const int r0 = blockIdx.x * 8;
    float* base = zden + (size_t)r0 * CODE_DIM;
    const float4 zero = make_float4(0.f, 0.f, 0.f, 0.f);
    for (int q = t; q < 8 * CODE_DIM / 4; q += 256)
        *(float4*)&base[q * 4] = zero;
    __syncthreads();
    const int rl = t >> 5, k = t & 31;
    int   idx = zidx[(size_t)(r0 + rl) * KSP + k];
    float v   = zval[(size_t)(r0 + rl) * KSP + k];
    base[(size_t)rl * CODE_DIM + idx] = v;
}

// ---------------------------------------------------------------------------
// recon: ascending-index fold of 32 nonzeros, f32 fmaf (np z@D.T faithful)
__global__ __launch_bounds__(128) void recon_kernel(const int* __restrict__ zidx,
                                                    const float* __restrict__ zval,
                                                    const float* __restrict__ Dt,
                                                    float* __restrict__ recon)
{
    const int t   = threadIdx.x;
    const int row = blockIdx.x;
    float4 acc = make_float4(0.f, 0.f, 0.f, 0.f);
    const int*   ip = zidx + (size_t)row * KSP;
    const float* vp = zval + (size_t)row * KSP;
    for (int k = 0; k < KSP; ++k) {
        int   j = ip[k];
        float v = vp[k];
        float4 d = *(const float4*)&Dt[(size_t)j * INPUT_DIM + t * 4];
        acc.x = fmaf(v, d.x, acc.x);
        acc.y = fmaf(v, d.y, acc.y);
        acc.z = fmaf(v, d.z, acc.z);
        acc.w = fmaf(v, d.w, acc.w);
    }
    *(float4*)&recon[(size_t)row * INPUT_DIM + t * 4] = acc;
}

// ---------------------------------------------------------------------------
extern "C" void kernel_launch(void* const* d_in, const int* in_sizes, int n_in,
                              void* d_out, int out_size, void* d_ws, size_t ws_size,
                              hipStream_t stream)
{
    const float* x = (const float*)d_in[0];
    const float* W = (const float*)d_in[1];   // [5][512][2048]
    const float* S = (const float*)d_in[2];   // [5][2048][2048]
    const float* D = (const float*)d_in[3];   // [512][2048]

    float* recon = (float*)d_out;
    float* zden  = (float*)d_out + (size_t)BATCH * INPUT_DIM;  // u scratch, then dense z

    int*   zidx = (int*)d_ws;
    float* zval = (float*)((char*)d_ws + (size_t)BATCH * KSP * 4);
    float* Dt   = (float*)((char*)d_ws + (size_t)2 * BATCH * KSP * 4);

    transpose_512x2048_kernel<<<dim3(CODE_DIM / 32, INPUT_DIM / 32), dim3(32, 8), 0, stream>>>(D, Dt);

    for (int l = 0; l < LAYERS; ++l) {
        const float* Wl = W + (size_t)l * INPUT_DIM * CODE_DIM;
        const float* Sl = (l == 0) ? nullptr : S + (size_t)l * CODE_DIM * CODE_DIM;
        gemm_layer_kernel<<<dim3(CODE_DIM / BN, BATCH / BM), 256, 0, stream>>>(
            x, Wl, Sl, (l == 0) ? nullptr : zidx, (l == 0) ? nullptr : zval, zden);
        topk32_wave_kernel<<<BATCH / 4, 256, 0, stream>>>(zden, zidx, zval);
    }

    zfill_scatter_kernel<<<BATCH / 8, 256, 0, stream>>>(zidx, zval, zden);
    recon_kernel<<<BATCH, 128, 0, stream>>>(zidx, zval, Dt, recon);
}